// Round 13
// baseline (385.258 us; speedup 1.0000x reference)
//
#include <hip/hip_runtime.h>

#define NN 20000      // nodes
#define NNP 20032     // padded rows (64-row GEMM tiles read past NN)
#define NH 128        // hidden
#define NG 64         // graphs
#define NLAY 3
#define NCH 5         // 4 splits + main
#define GEPS 1e-5f
#define GSLOPE 0.01f

typedef unsigned short u16;
typedef unsigned int u32;
typedef __attribute__((ext_vector_type(8))) short short8;
typedef __attribute__((ext_vector_type(4))) float float4v;
typedef __attribute__((ext_vector_type(2))) float f32x2;

__device__ __forceinline__ u16 f2bf(float f) {
  union { float f; u32 u; } v; v.f = f;
  u32 r = (v.u + 0x7fffu + ((v.u >> 16) & 1u)) >> 16;
  return (u16)r;
}

struct ZP {
  const u16* A[NCH];     // GEMM input (bf16, NNP rows, stride NH)
  const u16* W[NCH];     // GEMM weight, bf16 transposed [N][K]
  u16* Y[NCH];           // GEMM output / gather source (bf16)
  int ystride[NCH];      // row stride of Y in elements (256 for ydual, 128 else)
  u16* Xo[NCH];          // post-agg pre-norm (bf16, stride NH)
  u16* Xn[NCH];          // post-norm, next layer's A (null -> skip store)
  const float* bias[NCH];
  const float* gw[NCH];
  const float* gb[NCH];
  const float* gms[NCH];
  int colbase[NCH];
};

struct ES4 {
  const int* e[4];
  int cnt[4];
  int off[4];
};

// ---------------- setup kernels ----------------

// blocks 0..3: coalesced tile-wise exclusive scan of deg -> indptr (+cursor) + dinv.
// block 4: per-graph start/count via binary search (batch is sorted).
__global__ __launch_bounds__(1024) void k_scan(const int* __restrict__ deg,
                                               int* __restrict__ indptr,
                                               int* __restrict__ cursor,
                                               float* __restrict__ dinv,
                                               const int* __restrict__ batch,
                                               int* __restrict__ counts,
                                               int* __restrict__ gstart) {
  int s = blockIdx.x;
  int t = threadIdx.x;
  if (s == 4) {
    int g = t;
    if (g < NG) {
      auto lb = [&](int key) {
        int lo = 0, hi = NN;
        while (lo < hi) {
          int mid = (lo + hi) >> 1;
          if (batch[mid] < key) lo = mid + 1; else hi = mid;
        }
        return lo;
      };
      int a = lb(g), b = lb(g + 1);
      gstart[g] = a;
      counts[g] = b - a;
    }
    return;
  }
  const int* d = deg + s * NN;
  int* ip = indptr + s * (NN + 1);
  int* cu = cursor + s * (NN + 1);
  int lane = t & 63, wv = t >> 6;  // 16 waves
  __shared__ int wsum[16];
  int run = 0;
  const int NT = (NN + 1023) / 1024;  // 20
  for (int tile = 0; tile < NT; tile++) {
    int idx = tile * 1024 + t;
    int v = 0;
    if (idx < NN) {
      v = d[idx];
      dinv[s * NN + idx] = rsqrtf((float)v + 1.0f);
    }
    int x = v;
#pragma unroll
    for (int o = 1; o < 64; o <<= 1) {
      int y = __shfl_up(x, o);
      if (lane >= o) x += y;
    }
    if (lane == 63) wsum[wv] = x;
    __syncthreads();
    if (wv == 0) {
      int y = (lane < 16) ? wsum[lane] : 0;
#pragma unroll
      for (int o = 1; o < 16; o <<= 1) {
        int z = __shfl_up(y, o);
        if (lane >= o) y += z;
      }
      if (lane < 16) wsum[lane] = y;
    }
    __syncthreads();
    int waveoff = (wv == 0) ? 0 : wsum[wv - 1];
    int excl = run + waveoff + x - v;
    if (idx < NN) { ip[idx] = excl; cu[idx] = excl; }
    run += wsum[15];
    __syncthreads();
  }
  if (t == 0) { ip[NN] = run; cu[NN] = run; }
}

// packed entry: low 16 = src (NN < 2^16), high 16 = coef as bf16.
__global__ void k_fill(ES4 es, const float* __restrict__ dinv, int* __restrict__ cursor,
                       u32* __restrict__ ent) {
  int s = blockIdx.y;
  int i = blockIdx.x * 256 + threadIdx.x;
  int E = es.cnt[s];
  if (i >= E) return;
  int src = es.e[s][i];
  int dst = es.e[s][E + i];
  int pos = atomicAdd(&cursor[s * (NN + 1) + dst], 1);
  float c = dinv[s * NN + src] * dinv[s * NN + dst];
  ent[es.off[s] + pos] = (u32)src | ((u32)f2bf(c) << 16);
}

// fused setup: y<4 -> deg histogram for edge set y; y in 4..10 -> weight transpose
// fp32[K][N]->bf16[N][K] for mat y-4 (x<16).
__global__ __launch_bounds__(256) void k_setup(ES4 es, int* __restrict__ deg,
                                               const float* __restrict__ embW,
                                               const float* __restrict__ locW,
                                               const float* __restrict__ mainW,
                                               u16* __restrict__ wt) {
  int ybk = blockIdx.y;
  if (ybk < 4) {
    int s = ybk;
    int i = blockIdx.x * 256 + threadIdx.x;
    int E = es.cnt[s];
    if (i < E) atomicAdd(&deg[s * NN + es.e[s][E + i]], 1);
    return;
  }
  if (blockIdx.x >= 16) return;
  int mat = ybk - 4;
  const float* W = (mat == 0) ? embW : ((mat <= 3) ? locW + (mat - 1) * NH * NH
                                                   : mainW + (mat - 4) * NH * NH);
  int tile = blockIdx.x;
  int tk = (tile >> 2) * 32;
  int tn = (tile & 3) * 32;
  __shared__ float tl[32][33];
  int c = threadIdx.x & 31, r = threadIdx.x >> 5;
#pragma unroll
  for (int rr = 0; rr < 32; rr += 8)
    tl[r + rr][c] = W[(size_t)(tk + r + rr) * NH + tn + c];
  __syncthreads();
#pragma unroll
  for (int rr = 0; rr < 32; rr += 8)
    wt[(size_t)mat * NH * NH + (size_t)(tn + r + rr) * NH + tk + c] = f2bf(tl[c][r + rr]);
}

// ---------------- compute kernels ----------------

// Fused embedding + layer-0 GEMMs: per 64-row tile,
//   h = bf16(x) @ embW + embb       (h lives only in LDS, bf16)
//   ydual[:,0:128]   = h @ locW0    (shared by split chains 0..3)
//   ydual[:,128:256] = h @ mainW0
__global__ __launch_bounds__(256) void k_gemm0(const float* __restrict__ x,
                                               const u16* __restrict__ wt,
                                               const float* __restrict__ embb,
                                               u16* __restrict__ ydual) {
  __shared__ u16 As[64][136];
  __shared__ u16 Bs[128][136];
  int t = threadIdx.x;
  int row0 = blockIdx.x * 64;
  int c = t & 15, rs = t >> 4;
#pragma unroll
  for (int pass = 0; pass < 4; pass++) {
    int r = pass * 16 + rs;
    int gr = row0 + r;
    uint4 o = make_uint4(0, 0, 0, 0);
    if (gr < NN) {
      float4 a = *(const float4*)(x + (size_t)gr * NH + c * 8);
      float4 b = *(const float4*)(x + (size_t)gr * NH + c * 8 + 4);
      o.x = f2bf(a.x) | ((u32)f2bf(a.y) << 16);
      o.y = f2bf(a.z) | ((u32)f2bf(a.w) << 16);
      o.z = f2bf(b.x) | ((u32)f2bf(b.y) << 16);
      o.w = f2bf(b.z) | ((u32)f2bf(b.w) << 16);
    }
    *(uint4*)(&As[r][c * 8]) = o;
  }
#pragma unroll
  for (int pass = 0; pass < 8; pass++) {
    int n = pass * 16 + rs;
    *(uint4*)(&Bs[n][c * 8]) = *(const uint4*)(wt + (size_t)n * NH + c * 8);  // embW
  }
  __syncthreads();
  int lane = t & 63, w = t >> 6;
  int m16 = lane & 15, quad = lane >> 4;
  float4v acc[8];
#pragma unroll
  for (int i = 0; i < 8; i++) acc[i] = (float4v)(0.f);
#pragma unroll
  for (int kk = 0; kk < 4; kk++) {
    short8 av = *(const short8*)(&As[w * 16 + m16][kk * 32 + quad * 8]);
#pragma unroll
    for (int ct = 0; ct < 8; ct++) {
      short8 bv = *(const short8*)(&Bs[ct * 16 + m16][kk * 32 + quad * 8]);
      acc[ct] = __builtin_amdgcn_mfma_f32_16x16x32_bf16(av, bv, acc[ct], 0, 0, 0);
    }
  }
  __syncthreads();  // stage-1 LDS reads complete
#pragma unroll
  for (int ct = 0; ct < 8; ct++) {
    float bv = embb[ct * 16 + m16];
#pragma unroll
    for (int r = 0; r < 4; r++)
      As[w * 16 + quad * 4 + r][ct * 16 + m16] = f2bf(acc[ct][r] + bv);
  }
  {
    const u16* wl = wt + (size_t)1 * NH * NH;  // locW0
#pragma unroll
    for (int pass = 0; pass < 8; pass++) {
      int n = pass * 16 + rs;
      *(uint4*)(&Bs[n][c * 8]) = *(const uint4*)(wl + (size_t)n * NH + c * 8);
    }
  }
  __syncthreads();
  float4v acc0[8];
#pragma unroll
  for (int i = 0; i < 8; i++) acc0[i] = (float4v)(0.f);
#pragma unroll
  for (int kk = 0; kk < 4; kk++) {
    short8 av = *(const short8*)(&As[w * 16 + m16][kk * 32 + quad * 8]);
#pragma unroll
    for (int ct = 0; ct < 8; ct++) {
      short8 bv = *(const short8*)(&Bs[ct * 16 + m16][kk * 32 + quad * 8]);
      acc0[ct] = __builtin_amdgcn_mfma_f32_16x16x32_bf16(av, bv, acc0[ct], 0, 0, 0);
    }
  }
  __syncthreads();  // stage-2 Bs reads complete
  {
    const u16* wm = wt + (size_t)4 * NH * NH;  // mainW0
#pragma unroll
    for (int pass = 0; pass < 8; pass++) {
      int n = pass * 16 + rs;
      *(uint4*)(&Bs[n][c * 8]) = *(const uint4*)(wm + (size_t)n * NH + c * 8);
    }
  }
  __syncthreads();
  float4v acc4[8];
#pragma unroll
  for (int i = 0; i < 8; i++) acc4[i] = (float4v)(0.f);
#pragma unroll
  for (int kk = 0; kk < 4; kk++) {
    short8 av = *(const short8*)(&As[w * 16 + m16][kk * 32 + quad * 8]);
#pragma unroll
    for (int ct = 0; ct < 8; ct++) {
      short8 bv = *(const short8*)(&Bs[ct * 16 + m16][kk * 32 + quad * 8]);
      acc4[ct] = __builtin_amdgcn_mfma_f32_16x16x32_bf16(av, bv, acc4[ct], 0, 0, 0);
    }
  }
  __syncthreads();  // stage-3 LDS reads complete; As/Bs free for bounce
#pragma unroll
  for (int ct = 0; ct < 8; ct++) {
#pragma unroll
    for (int r = 0; r < 4; r++) {
      As[w * 16 + quad * 4 + r][ct * 16 + m16] = f2bf(acc0[ct][r]);
      Bs[w * 16 + quad * 4 + r][ct * 16 + m16] = f2bf(acc4[ct][r]);
    }
  }
  __syncthreads();
#pragma unroll
  for (int pass = 0; pass < 4; pass++) {
    int r = pass * 16 + rs;
    int gr = row0 + r;
    if (gr < NN) {
      *(uint4*)(ydual + (size_t)gr * 256 + c * 8) = *(const uint4*)(&As[r][c * 8]);
      *(uint4*)(ydual + (size_t)gr * 256 + 128 + c * 8) = *(const uint4*)(&Bs[r][c * 8]);
    }
  }
}

// Y[z] = A[z] @ Wt[z]^T. bf16 MFMA 16x16x32, 64-row tile, K=128 in LDS.
__global__ __launch_bounds__(256) void k_gemm_bf(ZP p) {
  int zi = blockIdx.y;
  const u16* __restrict__ A = p.A[zi];
  const u16* __restrict__ Wt = p.W[zi];
  u16* __restrict__ Y = p.Y[zi];
  int yst = p.ystride[zi];
  __shared__ u16 As[64][136];   // +8 pad: 2-way bank aliasing only
  __shared__ u16 Bs[128][136];
  int t = threadIdx.x;
  int row0 = blockIdx.x * 64;
  int c = t & 15, rs = t >> 4;
#pragma unroll
  for (int pass = 0; pass < 4; pass++) {
    int r = pass * 16 + rs;
    *(uint4*)(&As[r][c * 8]) = *(const uint4*)(A + (size_t)(row0 + r) * NH + c * 8);
  }
#pragma unroll
  for (int pass = 0; pass < 8; pass++) {
    int n = pass * 16 + rs;
    *(uint4*)(&Bs[n][c * 8]) = *(const uint4*)(Wt + (size_t)n * NH + c * 8);
  }
  __syncthreads();
  int lane = t & 63, w = t >> 6;
  int m16 = lane & 15, quad = lane >> 4;
  float4v acc[8];
#pragma unroll
  for (int i = 0; i < 8; i++) acc[i] = (float4v)(0.f);
#pragma unroll
  for (int kk = 0; kk < 4; kk++) {
    short8 av = *(const short8*)(&As[w * 16 + m16][kk * 32 + quad * 8]);
#pragma unroll
    for (int ct = 0; ct < 8; ct++) {
      short8 bv = *(const short8*)(&Bs[ct * 16 + m16][kk * 32 + quad * 8]);
      acc[ct] = __builtin_amdgcn_mfma_f32_16x16x32_bf16(av, bv, acc[ct], 0, 0, 0);
    }
  }
  __syncthreads();
  // epilogue: C/D layout col=lane&15, row=quad*4+reg -> LDS bounce -> 16B stores
#pragma unroll
  for (int ct = 0; ct < 8; ct++) {
#pragma unroll
    for (int r = 0; r < 4; r++) {
      As[w * 16 + quad * 4 + r][ct * 16 + m16] = f2bf(acc[ct][r]);
    }
  }
  __syncthreads();
#pragma unroll
  for (int pass = 0; pass < 4; pass++) {
    int r = pass * 16 + rs;
    int gr = row0 + r;
    if (gr < NN) *(uint4*)(Y + (size_t)gr * yst + c * 8) = *(const uint4*)(&As[r][c * 8]);
  }
}

__device__ __forceinline__ f32x2 bf2x2(u32 v) {
  f32x2 r;
  r.x = __uint_as_float(v << 16);
  r.y = __uint_as_float(v & 0xffff0000u);
  return r;
}

// packed float2 FMA payload (targets v_pk_fma_f32)
__device__ __forceinline__ void fma8p(f32x2* a, uint4 v, float cf) {
  f32x2 c2; c2.x = cf; c2.y = cf;
  a[0] += c2 * bf2x2(v.x);
  a[1] += c2 * bf2x2(v.y);
  a[2] += c2 * bf2x2(v.z);
  a[3] += c2 * bf2x2(v.w);
}

// self term + bias, pack -> Xo (no stats here: per-element global atomics are
// ~100x more expensive than per-block-reduced work on MI355X — round 7 lesson)
__device__ __forceinline__ void fin_chain(const float* a, const u16* Yb, int st, int node,
                                          int fo, float d2, const float* bias,
                                          u16* __restrict__ Xo) {
  uint4 sv = *(const uint4*)(Yb + (size_t)node * st + fo);
  float s[8] = {
    __uint_as_float(sv.x << 16), __uint_as_float(sv.x & 0xffff0000u),
    __uint_as_float(sv.y << 16), __uint_as_float(sv.y & 0xffff0000u),
    __uint_as_float(sv.z << 16), __uint_as_float(sv.z & 0xffff0000u),
    __uint_as_float(sv.w << 16), __uint_as_float(sv.w & 0xffff0000u)};
  float4 b0 = *(const float4*)(bias + fo);
  float4 b1 = *(const float4*)(bias + fo + 4);
  float bb[8] = {b0.x, b0.y, b0.z, b0.w, b1.x, b1.y, b1.z, b1.w};
  float o[8];
#pragma unroll
  for (int j = 0; j < 8; j++) o[j] = a[j] + d2 * s[j] + bb[j];
  uint4 ou;
  u32* op = (u32*)&ou;
#pragma unroll
  for (int j = 0; j < 4; j++)
    op[j] = (u32)f2bf(o[2 * j]) | ((u32)f2bf(o[2 * j + 1]) << 16);
  *(uint4*)(Xo + (size_t)node * NH + fo) = ou;
}

// GCN aggregate, 1-D grid (13750 blocks) with XCD-steered chain split:
//   blocks 0..9999: set-0 gather, ONE chain per block. oct = b&7:
//     oct<4 -> chain 0 (row bytes 0..255, XCDs 0..3 under blockIdx%8 round-robin),
//     oct>=4 -> chain 4 (bytes 256..511, XCDs 4..7). Halves per-XCD L2 working set.
//     4 nodes/block (wave each), 4 edge-groups x 16 lanes, 2x unroll + shuffle.
//   blocks 10000..13749: MST chain 1..3 (avg deg~2), 16 nodes/block:
//     one 16-lane group per node, serial loop, no shuffles.
__global__ __launch_bounds__(256) void k_agg2(ZP p, const int* __restrict__ indptr,
                                              const u32* __restrict__ ent,
                                              const float* __restrict__ dinv, int4 entoff) {
  int b = blockIdx.x;
  int wv = threadIdx.x >> 6, lane = threadIdx.x & 63;
  int g = lane >> 4;
  int fo = (lane & 15) * 8;
  if (b < 10000) {
    int oct = b & 7;
    int chain = (oct < 4) ? 0 : 4;
    int grp = (b >> 3) * 4 + (oct & 3);  // 0..4999, bijective per chain
    int node = grp * 4 + wv;
    int beg = indptr[node], end = indptr[node + 1];
    const u16* __restrict__ Y = p.Y[chain];
    int st = p.ystride[chain];
    f32x2 a[4];
#pragma unroll
    for (int j = 0; j < 4; j++) a[j] = (f32x2)(0.f);
    int e = beg + g;
    for (; e + 4 < end; e += 8) {
      u32 sa = ent[e];
      u32 sb = ent[e + 4];
      uint4 va = *(const uint4*)(Y + (size_t)(sa & 0xffffu) * st + fo);
      uint4 vb = *(const uint4*)(Y + (size_t)(sb & 0xffffu) * st + fo);
      fma8p(a, va, __uint_as_float(sa & 0xffff0000u));
      fma8p(a, vb, __uint_as_float(sb & 0xffff0000u));
    }
    if (e < end) {
      u32 sc = ent[e];
      uint4 v = *(const uint4*)(Y + (size_t)(sc & 0xffffu) * st + fo);
      fma8p(a, v, __uint_as_float(sc & 0xffff0000u));
    }
    float* fa = (float*)a;
#pragma unroll
    for (int j = 0; j < 8; j++) {
      fa[j] += __shfl_xor(fa[j], 16);
      fa[j] += __shfl_xor(fa[j], 32);
    }
    if (g == 0) {
      float di = dinv[node];
      float d2 = di * di;
      fin_chain(fa, Y, st, node, fo, d2, p.bias[chain], p.Xo[chain]);
    }
  } else {
    int mb = b - 10000;
    int s = 1 + mb / 1250;       // chain == edge set, 1..3
    int node = (mb % 1250) * 16 + wv * 4 + g;  // 1250*16 == NN exactly
    const int* ip = indptr + s * (NN + 1);
    int eb = (s == 1) ? entoff.y : ((s == 2) ? entoff.z : entoff.w);
    const u16* __restrict__ Y = p.Y[s];
    int st = p.ystride[s];
    int beg = ip[node], end = ip[node + 1];
    const u32* __restrict__ ev = ent + eb;
    f32x2 a[4];
#pragma unroll
    for (int j = 0; j < 4; j++) a[j] = (f32x2)(0.f);
    for (int e = beg; e < end; e++) {
      u32 sc = ev[e];  // same addr across the 16-lane group -> one fetch
      uint4 v = *(const uint4*)(Y + (size_t)(sc & 0xffffu) * st + fo);
      fma8p(a, v, __uint_as_float(sc & 0xffff0000u));
    }
    float di = dinv[s * NN + node];
    float d2 = di * di;
    fin_chain((float*)a, Y, st, node, fo, d2, p.bias[s], p.Xo[s]);
  }
}

// fused graph-norm: grid (NG, NCH, 4 feature-chunks), 256 thr = 16 feature-pairs
// x 16 row-streams. Two passes over the graph's contiguous row slab (batch is
// sorted): stats via LDS tree (zero atomics), then normalize+leaky -> Xn and
// per-graph M-row by DIRECT store (each (g,col) owned by exactly one block).
__global__ __launch_bounds__(256) void k_norm2(ZP p, const int* __restrict__ gstart,
                                               const int* __restrict__ counts,
                                               float* __restrict__ Ml) {
  int g = blockIdx.x, zi = blockIdx.y, fc = blockIdx.z;
  const u16* __restrict__ X = p.Xo[zi];
  u16* __restrict__ Xn = p.Xn[zi];
  int t = threadIdx.x;
  int fj = t & 15;
  int f2 = fc * 32 + fj * 2;
  int rh = t >> 4;  // 16 row streams
  int start = gstart[g], cnt = counts[g];
  __shared__ float red[4][16][17];
  float s0 = 0.f, s1 = 0.f, q0 = 0.f, q1 = 0.f;
  for (int i = rh; i < cnt; i += 16) {
    u32 v = *(const u32*)(X + (size_t)(start + i) * NH + f2);
    float v0 = __uint_as_float(v << 16), v1 = __uint_as_float(v & 0xffff0000u);
    s0 += v0; q0 += v0 * v0;
    s1 += v1; q1 += v1 * v1;
  }
  red[0][rh][fj] = s0; red[1][rh][fj] = s1;
  red[2][rh][fj] = q0; red[3][rh][fj] = q1;
  __syncthreads();
#pragma unroll
  for (int off = 8; off >= 1; off >>= 1) {
    if (rh < off) {
      red[0][rh][fj] += red[0][rh + off][fj];
      red[1][rh][fj] += red[1][rh + off][fj];
      red[2][rh][fj] += red[2][rh + off][fj];
      red[3][rh][fj] += red[3][rh + off][fj];
    }
    __syncthreads();
  }
  float cntf = fmaxf((float)cnt, 1.f);
  float w0 = p.gw[zi][f2], w1 = p.gw[zi][f2 + 1];
  float b0 = p.gb[zi][f2], b1 = p.gb[zi][f2 + 1];
  float ms0 = p.gms[zi][f2], ms1 = p.gms[zi][f2 + 1];
  float mean0 = red[0][0][fj] / cntf, mean1 = red[1][0][fj] / cntf;
  float var0 = red[2][0][fj] / cntf - (2.f * ms0 - ms0 * ms0) * mean0 * mean0;
  float var1 = red[3][0][fj] / cntf - (2.f * ms1 - ms1 * ms1) * mean1 * mean1;
  float inv0 = rsqrtf(var0 + GEPS), inv1 = rsqrtf(var1 + GEPS);
  __syncthreads();  // all reads of red done before reuse
  float m0 = 0.f, m1 = 0.f;
  for (int i = rh; i < cnt; i += 16) {
    size_t ro = (size_t)(start + i) * NH + f2;
    u32 v = *(const u32*)(X + ro);
    float v0 = __uint_as_float(v << 16), v1 = __uint_as_float(v & 0xffff0000u);
    float o0 = w0 * (v0 - ms0 * mean0) * inv0 + b0;
    float o1 = w1 * (v1 - ms1 * mean1) * inv1 + b1;
    o0 = (o0 >= 0.f) ? o0 : GSLOPE * o0;
    o1 = (o1 >= 0.f) ? o1 : GSLOPE * o1;
    if (Xn) *(u32*)(Xn + ro) = (u32)f2bf(o0) | ((u32)f2bf(o1) << 16);
    m0 += o0; m1 += o1;
  }
  red[0][rh][fj] = m0; red[1][rh][fj] = m1;
  __syncthreads();
#pragma unroll
  for (int off = 8; off >= 1; off >>= 1) {
    if (rh < off) {
      red[0][rh][fj] += red[0][rh + off][fj];
      red[1][rh][fj] += red[1][rh + off][fj];
    }
    __syncthreads();
  }
  if (rh == 0) {
    int col = p.colbase[zi] + f2;
    Ml[(size_t)g * 640 + col] = red[0][0][fj];
    Ml[(size_t)g * 640 + col + 1] = red[1][0][fj];
  }
}

// out[g][f] = mean_l(M[l][g][:] @ mergeW[:,f]) / cnt + mergeb[f]
__global__ __launch_bounds__(256) void k_mergeout(const float* __restrict__ M,
                                                  const float* __restrict__ mergeW,
                                                  const float* __restrict__ mergeb,
                                                  const int* __restrict__ counts,
                                                  float* __restrict__ out) {
  int g = blockIdx.x;
  int f = threadIdx.x & 127, h = threadIdx.x >> 7;
  __shared__ float mrow[640];
  __shared__ float red[128];
  float acc = 0.f;
  for (int l = 0; l < NLAY; l++) {
    const float* Mr = M + ((size_t)l * NG + g) * 640;
    for (int i = threadIdx.x; i < 640; i += 256) mrow[i] = Mr[i];
    __syncthreads();
    float s = 0.f;
    int k0 = h * 320;
#pragma unroll 8
    for (int k = k0; k < k0 + 320; k++) s += mrow[k] * mergeW[(size_t)k * NH + f];
    if (h) red[f] = s;
    __syncthreads();
    if (!h) acc += s + red[f];
    __syncthreads();
  }
  if (!h) {
    float cnt = fmaxf((float)counts[g], 1.f);
    out[(size_t)g * NH + f] = acc / (3.f * cnt) + mergeb[f];
  }
}

// ---------------- host ----------------

struct Offs {
  size_t counts, gstart, deg, M, dinv, indptr, cursor, ent, wt, ydual;
  size_t yb[NCH], xo[NCH], xn[NCH];
  size_t memset1_off, memset1_len, total;
};

static size_t build_offs(Offs& o, int Etot) {
  size_t off = 0;
  auto alloc = [&](size_t bytes) -> size_t {
    off = (off + 255) & ~(size_t)255;
    size_t s = off;
    off += bytes;
    return s;
  };
  o.counts = alloc(NG * 4);
  o.gstart = alloc(NG * 4);
  o.deg = alloc((size_t)4 * NN * 4);
  o.memset1_off = o.deg;
  o.memset1_len = (size_t)4 * NN * 4;  // only deg needs zeroing
  o.M = alloc((size_t)NLAY * NG * 640 * 4);  // fully overwritten by k_norm2
  o.dinv = alloc((size_t)4 * NN * 4);
  o.indptr = alloc((size_t)4 * (NN + 1) * 4);
  o.cursor = alloc((size_t)4 * (NN + 1) * 4);
  o.ent = alloc((size_t)Etot * 4);  // packed 4B entries
  o.wt = alloc((size_t)7 * NH * NH * 2);
  o.ydual = alloc((size_t)NN * 256 * 2);  // chains 0&4 interleaved
  for (int i = 1; i < 4; i++) o.yb[i] = alloc((size_t)NN * NH * 2);
  for (int i = 0; i < NCH; i++) {
    o.xo[i] = alloc((size_t)NN * NH * 2);
    o.xn[i] = alloc((size_t)NNP * NH * 2);
  }
  o.total = off;
  return off;
}

extern "C" void kernel_launch(void* const* d_in, const int* in_sizes, int n_in,
                              void* d_out, int out_size, void* d_ws, size_t ws_size,
                              hipStream_t stream) {
  if (n_in < 21) return;
  const float* x = (const float*)d_in[0];
  const float* embW = (const float*)d_in[1];
  const float* embb = (const float*)d_in[2];
  const float* mainW = (const float*)d_in[3];
  const float* mainb = (const float*)d_in[4];
  const float* maingw = (const float*)d_in[5];
  const float* maingb = (const float*)d_in[6];
  const float* maingms = (const float*)d_in[7];
  const float* locW = (const float*)d_in[8];
  const float* locb = (const float*)d_in[9];
  const float* locgw = (const float*)d_in[10];
  const float* locgb = (const float*)d_in[11];
  const float* locgms = (const float*)d_in[12];
  const float* mergeW = (const float*)d_in[13];
  const float* mergeb = (const float*)d_in[14];
  const int* edge_index = (const int*)d_in[15];
  // d_in[16] = edges0: permutation of edge_index under segment_sum -> reuse set 0
  const int* edges1 = (const int*)d_in[17];
  const int* edges2 = (const int*)d_in[18];
  const int* edges3 = (const int*)d_in[19];
  const int* batch = (const int*)d_in[20];

  int E0 = in_sizes[15] / 2;
  int E1 = in_sizes[17] / 2, E2 = in_sizes[18] / 2, E3 = in_sizes[19] / 2;
  int Etot = E0 + E1 + E2 + E3;
  int maxE = E0 > E1 ? E0 : E1;
  maxE = maxE > E2 ? maxE : E2;
  maxE = maxE > E3 ? maxE : E3;

  Offs o;
  if (build_offs(o, Etot) > ws_size) return;  // fail visibly

  char* ws = (char*)d_ws;
  int* counts = (int*)(ws + o.counts);
  int* gstart = (int*)(ws + o.gstart);
  int* deg = (int*)(ws + o.deg);
  float* M = (float*)(ws + o.M);
  float* dinv = (float*)(ws + o.dinv);
  int* indptr = (int*)(ws + o.indptr);
  int* cursor = (int*)(ws + o.cursor);
  u32* ent = (u32*)(ws + o.ent);
  u16* wt = (u16*)(ws + o.wt);
  u16* ydual = (u16*)(ws + o.ydual);
  u16 *yb[NCH], *xo[NCH], *xn[NCH];
  for (int i = 1; i < 4; i++) yb[i] = (u16*)(ws + o.yb[i]);
  for (int i = 0; i < NCH; i++) {
    xo[i] = (u16*)(ws + o.xo[i]);
    xn[i] = (u16*)(ws + o.xn[i]);
  }

  ES4 es;
  es.e[0] = edge_index; es.e[1] = edges1; es.e[2] = edges2; es.e[3] = edges3;
  es.cnt[0] = E0; es.cnt[1] = E1; es.cnt[2] = E2; es.cnt[3] = E3;
  es.off[0] = 0; es.off[1] = E0; es.off[2] = E0 + E1; es.off[3] = E0 + E1 + E2;
  int4 entoff = make_int4(0, E0, E0 + E1, E0 + E1 + E2);

  hipMemsetAsync(ws + o.memset1_off, 0, o.memset1_len, stream);  // deg only
  k_setup<<<dim3((maxE + 255) / 256, 11), 256, 0, stream>>>(es, deg, embW, locW, mainW, wt);
  k_scan<<<5, 1024, 0, stream>>>(deg, indptr, cursor, dinv, batch, counts, gstart);
  k_fill<<<dim3((maxE + 255) / 256, 4), 256, 0, stream>>>(es, dinv, cursor, ent);

  const int nrb = (NN + 63) / 64;  // 313

  // fused embedding + layer-0 GEMMs -> ydual (both halves)
  k_gemm0<<<nrb, 256, 0, stream>>>(x, wt, embb, ydual);

  for (int l = 0; l < NLAY; l++) {
    ZP p = {};
    for (int zi = 0; zi < NCH; zi++) {
      bool isMain = (zi == 4);
      p.A[zi] = (const u16*)xn[zi];
      p.W[zi] = wt + (size_t)((isMain ? 4 : 1) + l) * NH * NH;
      if (zi == 0) { p.Y[0] = ydual; p.ystride[0] = 256; }
      else if (zi == 4) { p.Y[4] = ydual + 128; p.ystride[4] = 256; }
      else { p.Y[zi] = yb[zi]; p.ystride[zi] = 128; }
      p.Xo[zi] = xo[zi];
      p.Xn[zi] = (l == NLAY - 1) ? (u16*)nullptr : xn[zi];
      p.bias[zi] = (isMain ? mainb : locb) + (size_t)l * NH;
      p.gw[zi] = (isMain ? maingw : locgw) + (size_t)l * NH;
      p.gb[zi] = (isMain ? maingb : locgb) + (size_t)l * NH;
      p.gms[zi] = (isMain ? maingms : locgms) + (size_t)l * NH;
      p.colbase[zi] = isMain ? 512 : zi * NH;
    }
    if (l == 0) {
      // k_gemm0 already produced ydual; MST chains gather from chain-0 half
      p.Y[1] = ydual; p.Y[2] = ydual; p.Y[3] = ydual;
      p.ystride[1] = p.ystride[2] = p.ystride[3] = 256;
    } else {
      k_gemm_bf<<<dim3(nrb, NCH), 256, 0, stream>>>(p);
    }
    k_agg2<<<13750, 256, 0, stream>>>(p, indptr, ent, dinv, entoff);
    k_norm2<<<dim3(NG, NCH, 4), 256, 0, stream>>>(p, gstart, counts,
                                                  M + (size_t)l * NG * 640);
  }

  k_mergeout<<<NG, 256, 0, stream>>>(M, mergeW, mergeb, counts, (float*)d_out);
}

// Round 14
// 379.435 us; speedup vs baseline: 1.0153x; 1.0153x over previous
//
#include <hip/hip_runtime.h>

#define NN 20000      // nodes
#define NNP 20032     // padded rows (64-row GEMM tiles read past NN)
#define NH 128        // hidden
#define NG 64         // graphs
#define NLAY 3
#define NCH 5         // 4 splits + main
#define GEPS 1e-5f
#define GSLOPE 0.01f

typedef unsigned short u16;
typedef unsigned int u32;
typedef __attribute__((ext_vector_type(8))) short short8;
typedef __attribute__((ext_vector_type(4))) float float4v;
typedef __attribute__((ext_vector_type(2))) float f32x2;

__device__ __forceinline__ u16 f2bf(float f) {
  union { float f; u32 u; } v; v.f = f;
  u32 r = (v.u + 0x7fffu + ((v.u >> 16) & 1u)) >> 16;
  return (u16)r;
}

struct ZP {
  const u16* A[NCH];     // GEMM input (bf16, NNP rows, stride NH)
  const u16* W[NCH];     // GEMM weight, bf16 transposed [N][K]
  u16* Y[NCH];           // GEMM output / gather source (bf16)
  int ystride[NCH];      // row stride of Y in elements (256 for ydual, 128 else)
  u16* Xo[NCH];          // post-agg pre-norm (bf16, stride NH)
  u16* Xn[NCH];          // post-norm, next layer's A (null -> skip store)
  const float* bias[NCH];
  const float* gw[NCH];
  const float* gb[NCH];
  const float* gms[NCH];
  int colbase[NCH];
};

struct ES4 {
  const int* e[4];
  int cnt[4];
  int off[4];
};

// ---------------- setup kernels ----------------

// blocks 0..3: coalesced tile-wise exclusive scan of deg -> indptr (+cursor) + dinv.
// block 4: per-graph start/count via binary search (batch is sorted).
__global__ __launch_bounds__(1024) void k_scan(const int* __restrict__ deg,
                                               int* __restrict__ indptr,
                                               int* __restrict__ cursor,
                                               float* __restrict__ dinv,
                                               const int* __restrict__ batch,
                                               int* __restrict__ counts,
                                               int* __restrict__ gstart) {
  int s = blockIdx.x;
  int t = threadIdx.x;
  if (s == 4) {
    int g = t;
    if (g < NG) {
      auto lb = [&](int key) {
        int lo = 0, hi = NN;
        while (lo < hi) {
          int mid = (lo + hi) >> 1;
          if (batch[mid] < key) lo = mid + 1; else hi = mid;
        }
        return lo;
      };
      int a = lb(g), b = lb(g + 1);
      gstart[g] = a;
      counts[g] = b - a;
    }
    return;
  }
  const int* d = deg + s * NN;
  int* ip = indptr + s * (NN + 1);
  int* cu = cursor + s * (NN + 1);
  int lane = t & 63, wv = t >> 6;  // 16 waves
  __shared__ int wsum[16];
  int run = 0;
  const int NT = (NN + 1023) / 1024;  // 20
  for (int tile = 0; tile < NT; tile++) {
    int idx = tile * 1024 + t;
    int v = 0;
    if (idx < NN) {
      v = d[idx];
      dinv[s * NN + idx] = rsqrtf((float)v + 1.0f);
    }
    int x = v;
#pragma unroll
    for (int o = 1; o < 64; o <<= 1) {
      int y = __shfl_up(x, o);
      if (lane >= o) x += y;
    }
    if (lane == 63) wsum[wv] = x;
    __syncthreads();
    if (wv == 0) {
      int y = (lane < 16) ? wsum[lane] : 0;
#pragma unroll
      for (int o = 1; o < 16; o <<= 1) {
        int z = __shfl_up(y, o);
        if (lane >= o) y += z;
      }
      if (lane < 16) wsum[lane] = y;
    }
    __syncthreads();
    int waveoff = (wv == 0) ? 0 : wsum[wv - 1];
    int excl = run + waveoff + x - v;
    if (idx < NN) { ip[idx] = excl; cu[idx] = excl; }
    run += wsum[15];
    __syncthreads();
  }
  if (t == 0) { ip[NN] = run; cu[NN] = run; }
}

// packed entry: low 16 = src (NN < 2^16), high 16 = coef as bf16.
__global__ void k_fill(ES4 es, const float* __restrict__ dinv, int* __restrict__ cursor,
                       u32* __restrict__ ent) {
  int s = blockIdx.y;
  int i = blockIdx.x * 256 + threadIdx.x;
  int E = es.cnt[s];
  if (i >= E) return;
  int src = es.e[s][i];
  int dst = es.e[s][E + i];
  int pos = atomicAdd(&cursor[s * (NN + 1) + dst], 1);
  float c = dinv[s * NN + src] * dinv[s * NN + dst];
  ent[es.off[s] + pos] = (u32)src | ((u32)f2bf(c) << 16);
}

// fused setup: y<4 -> deg histogram for edge set y; y in 4..10 -> weight transpose
// fp32[K][N]->bf16[N][K] for mat y-4 (x<16).
__global__ __launch_bounds__(256) void k_setup(ES4 es, int* __restrict__ deg,
                                               const float* __restrict__ embW,
                                               const float* __restrict__ locW,
                                               const float* __restrict__ mainW,
                                               u16* __restrict__ wt) {
  int ybk = blockIdx.y;
  if (ybk < 4) {
    int s = ybk;
    int i = blockIdx.x * 256 + threadIdx.x;
    int E = es.cnt[s];
    if (i < E) atomicAdd(&deg[s * NN + es.e[s][E + i]], 1);
    return;
  }
  if (blockIdx.x >= 16) return;
  int mat = ybk - 4;
  const float* W = (mat == 0) ? embW : ((mat <= 3) ? locW + (mat - 1) * NH * NH
                                                   : mainW + (mat - 4) * NH * NH);
  int tile = blockIdx.x;
  int tk = (tile >> 2) * 32;
  int tn = (tile & 3) * 32;
  __shared__ float tl[32][33];
  int c = threadIdx.x & 31, r = threadIdx.x >> 5;
#pragma unroll
  for (int rr = 0; rr < 32; rr += 8)
    tl[r + rr][c] = W[(size_t)(tk + r + rr) * NH + tn + c];
  __syncthreads();
#pragma unroll
  for (int rr = 0; rr < 32; rr += 8)
    wt[(size_t)mat * NH * NH + (size_t)(tn + r + rr) * NH + tk + c] = f2bf(tl[c][r + rr]);
}

// ---------------- compute kernels ----------------

// Fused embedding + layer-0 GEMMs: per 64-row tile,
//   h = bf16(x) @ embW + embb       (h lives only in LDS, bf16)
//   ydual[:,0:128]   = h @ locW0    (shared by split chains 0..3)
//   ydual[:,128:256] = h @ mainW0
__global__ __launch_bounds__(256) void k_gemm0(const float* __restrict__ x,
                                               const u16* __restrict__ wt,
                                               const float* __restrict__ embb,
                                               u16* __restrict__ ydual) {
  __shared__ u16 As[64][136];
  __shared__ u16 Bs[128][136];
  int t = threadIdx.x;
  int row0 = blockIdx.x * 64;
  int c = t & 15, rs = t >> 4;
#pragma unroll
  for (int pass = 0; pass < 4; pass++) {
    int r = pass * 16 + rs;
    int gr = row0 + r;
    uint4 o = make_uint4(0, 0, 0, 0);
    if (gr < NN) {
      float4 a = *(const float4*)(x + (size_t)gr * NH + c * 8);
      float4 b = *(const float4*)(x + (size_t)gr * NH + c * 8 + 4);
      o.x = f2bf(a.x) | ((u32)f2bf(a.y) << 16);
      o.y = f2bf(a.z) | ((u32)f2bf(a.w) << 16);
      o.z = f2bf(b.x) | ((u32)f2bf(b.y) << 16);
      o.w = f2bf(b.z) | ((u32)f2bf(b.w) << 16);
    }
    *(uint4*)(&As[r][c * 8]) = o;
  }
#pragma unroll
  for (int pass = 0; pass < 8; pass++) {
    int n = pass * 16 + rs;
    *(uint4*)(&Bs[n][c * 8]) = *(const uint4*)(wt + (size_t)n * NH + c * 8);  // embW
  }
  __syncthreads();
  int lane = t & 63, w = t >> 6;
  int m16 = lane & 15, quad = lane >> 4;
  float4v acc[8];
#pragma unroll
  for (int i = 0; i < 8; i++) acc[i] = (float4v)(0.f);
#pragma unroll
  for (int kk = 0; kk < 4; kk++) {
    short8 av = *(const short8*)(&As[w * 16 + m16][kk * 32 + quad * 8]);
#pragma unroll
    for (int ct = 0; ct < 8; ct++) {
      short8 bv = *(const short8*)(&Bs[ct * 16 + m16][kk * 32 + quad * 8]);
      acc[ct] = __builtin_amdgcn_mfma_f32_16x16x32_bf16(av, bv, acc[ct], 0, 0, 0);
    }
  }
  __syncthreads();  // stage-1 LDS reads complete
#pragma unroll
  for (int ct = 0; ct < 8; ct++) {
    float bv = embb[ct * 16 + m16];
#pragma unroll
    for (int r = 0; r < 4; r++)
      As[w * 16 + quad * 4 + r][ct * 16 + m16] = f2bf(acc[ct][r] + bv);
  }
  {
    const u16* wl = wt + (size_t)1 * NH * NH;  // locW0
#pragma unroll
    for (int pass = 0; pass < 8; pass++) {
      int n = pass * 16 + rs;
      *(uint4*)(&Bs[n][c * 8]) = *(const uint4*)(wl + (size_t)n * NH + c * 8);
    }
  }
  __syncthreads();
  float4v acc0[8];
#pragma unroll
  for (int i = 0; i < 8; i++) acc0[i] = (float4v)(0.f);
#pragma unroll
  for (int kk = 0; kk < 4; kk++) {
    short8 av = *(const short8*)(&As[w * 16 + m16][kk * 32 + quad * 8]);
#pragma unroll
    for (int ct = 0; ct < 8; ct++) {
      short8 bv = *(const short8*)(&Bs[ct * 16 + m16][kk * 32 + quad * 8]);
      acc0[ct] = __builtin_amdgcn_mfma_f32_16x16x32_bf16(av, bv, acc0[ct], 0, 0, 0);
    }
  }
  __syncthreads();  // stage-2 Bs reads complete
  {
    const u16* wm = wt + (size_t)4 * NH * NH;  // mainW0
#pragma unroll
    for (int pass = 0; pass < 8; pass++) {
      int n = pass * 16 + rs;
      *(uint4*)(&Bs[n][c * 8]) = *(const uint4*)(wm + (size_t)n * NH + c * 8);
    }
  }
  __syncthreads();
  float4v acc4[8];
#pragma unroll
  for (int i = 0; i < 8; i++) acc4[i] = (float4v)(0.f);
#pragma unroll
  for (int kk = 0; kk < 4; kk++) {
    short8 av = *(const short8*)(&As[w * 16 + m16][kk * 32 + quad * 8]);
#pragma unroll
    for (int ct = 0; ct < 8; ct++) {
      short8 bv = *(const short8*)(&Bs[ct * 16 + m16][kk * 32 + quad * 8]);
      acc4[ct] = __builtin_amdgcn_mfma_f32_16x16x32_bf16(av, bv, acc4[ct], 0, 0, 0);
    }
  }
  __syncthreads();  // stage-3 LDS reads complete; As/Bs free for bounce
#pragma unroll
  for (int ct = 0; ct < 8; ct++) {
#pragma unroll
    for (int r = 0; r < 4; r++) {
      As[w * 16 + quad * 4 + r][ct * 16 + m16] = f2bf(acc0[ct][r]);
      Bs[w * 16 + quad * 4 + r][ct * 16 + m16] = f2bf(acc4[ct][r]);
    }
  }
  __syncthreads();
#pragma unroll
  for (int pass = 0; pass < 4; pass++) {
    int r = pass * 16 + rs;
    int gr = row0 + r;
    if (gr < NN) {
      *(uint4*)(ydual + (size_t)gr * 256 + c * 8) = *(const uint4*)(&As[r][c * 8]);
      *(uint4*)(ydual + (size_t)gr * 256 + 128 + c * 8) = *(const uint4*)(&Bs[r][c * 8]);
    }
  }
}

// Y[z] = A[z] @ Wt[z]^T. bf16 MFMA 16x16x32, 64-row tile, K=128 in LDS.
__global__ __launch_bounds__(256) void k_gemm_bf(ZP p) {
  int zi = blockIdx.y;
  const u16* __restrict__ A = p.A[zi];
  const u16* __restrict__ Wt = p.W[zi];
  u16* __restrict__ Y = p.Y[zi];
  int yst = p.ystride[zi];
  __shared__ u16 As[64][136];   // +8 pad: 2-way bank aliasing only
  __shared__ u16 Bs[128][136];
  int t = threadIdx.x;
  int row0 = blockIdx.x * 64;
  int c = t & 15, rs = t >> 4;
#pragma unroll
  for (int pass = 0; pass < 4; pass++) {
    int r = pass * 16 + rs;
    *(uint4*)(&As[r][c * 8]) = *(const uint4*)(A + (size_t)(row0 + r) * NH + c * 8);
  }
#pragma unroll
  for (int pass = 0; pass < 8; pass++) {
    int n = pass * 16 + rs;
    *(uint4*)(&Bs[n][c * 8]) = *(const uint4*)(Wt + (size_t)n * NH + c * 8);
  }
  __syncthreads();
  int lane = t & 63, w = t >> 6;
  int m16 = lane & 15, quad = lane >> 4;
  float4v acc[8];
#pragma unroll
  for (int i = 0; i < 8; i++) acc[i] = (float4v)(0.f);
#pragma unroll
  for (int kk = 0; kk < 4; kk++) {
    short8 av = *(const short8*)(&As[w * 16 + m16][kk * 32 + quad * 8]);
#pragma unroll
    for (int ct = 0; ct < 8; ct++) {
      short8 bv = *(const short8*)(&Bs[ct * 16 + m16][kk * 32 + quad * 8]);
      acc[ct] = __builtin_amdgcn_mfma_f32_16x16x32_bf16(av, bv, acc[ct], 0, 0, 0);
    }
  }
  __syncthreads();
  // epilogue: C/D layout col=lane&15, row=quad*4+reg -> LDS bounce -> 16B stores
#pragma unroll
  for (int ct = 0; ct < 8; ct++) {
#pragma unroll
    for (int r = 0; r < 4; r++) {
      As[w * 16 + quad * 4 + r][ct * 16 + m16] = f2bf(acc[ct][r]);
    }
  }
  __syncthreads();
#pragma unroll
  for (int pass = 0; pass < 4; pass++) {
    int r = pass * 16 + rs;
    int gr = row0 + r;
    if (gr < NN) *(uint4*)(Y + (size_t)gr * yst + c * 8) = *(const uint4*)(&As[r][c * 8]);
  }
}

__device__ __forceinline__ f32x2 bf2x2(u32 v) {
  f32x2 r;
  r.x = __uint_as_float(v << 16);
  r.y = __uint_as_float(v & 0xffff0000u);
  return r;
}

// packed float2 FMA payload (targets v_pk_fma_f32)
__device__ __forceinline__ void fma8p(f32x2* a, uint4 v, float cf) {
  f32x2 c2; c2.x = cf; c2.y = cf;
  a[0] += c2 * bf2x2(v.x);
  a[1] += c2 * bf2x2(v.y);
  a[2] += c2 * bf2x2(v.z);
  a[3] += c2 * bf2x2(v.w);
}

// self term + bias, pack -> Xo (no stats here: per-element global atomics are
// ~100x more expensive than per-block-reduced work on MI355X — round 7 lesson)
__device__ __forceinline__ void fin_chain(const float* a, const u16* Yb, int st, int node,
                                          int fo, float d2, const float* bias,
                                          u16* __restrict__ Xo) {
  uint4 sv = *(const uint4*)(Yb + (size_t)node * st + fo);
  float s[8] = {
    __uint_as_float(sv.x << 16), __uint_as_float(sv.x & 0xffff0000u),
    __uint_as_float(sv.y << 16), __uint_as_float(sv.y & 0xffff0000u),
    __uint_as_float(sv.z << 16), __uint_as_float(sv.z & 0xffff0000u),
    __uint_as_float(sv.w << 16), __uint_as_float(sv.w & 0xffff0000u)};
  float4 b0 = *(const float4*)(bias + fo);
  float4 b1 = *(const float4*)(bias + fo + 4);
  float bb[8] = {b0.x, b0.y, b0.z, b0.w, b1.x, b1.y, b1.z, b1.w};
  float o[8];
#pragma unroll
  for (int j = 0; j < 8; j++) o[j] = a[j] + d2 * s[j] + bb[j];
  uint4 ou;
  u32* op = (u32*)&ou;
#pragma unroll
  for (int j = 0; j < 4; j++)
    op[j] = (u32)f2bf(o[2 * j]) | ((u32)f2bf(o[2 * j + 1]) << 16);
  *(uint4*)(Xo + (size_t)node * NH + fo) = ou;
}

// GCN aggregate, compacted 1-D grid (8750 blocks) — round-12 measured optimum:
//   blocks 0..4999: chains 0&4 FUSED on interleaved ydual (shared entry loads +
//     addr math), 4 nodes/block (wave each), 4 edge-groups x 16 lanes,
//     2x unroll + shuffle reduce.
//   blocks 5000..8749: MST chain 1..3 (avg deg~2), 16 nodes/block:
//     one 16-lane group per node, serial loop, no shuffles.
// (XCD-steered chain split tried r13: neutral-to-worse — entry-load sharing
//  beats per-XCD working-set halving; gather is latency-bound, not L2-bound.)
__global__ __launch_bounds__(256) void k_agg2(ZP p, const int* __restrict__ indptr,
                                              const u32* __restrict__ ent,
                                              const float* __restrict__ dinv, int4 entoff) {
  int b = blockIdx.x;
  int wv = threadIdx.x >> 6, lane = threadIdx.x & 63;
  int g = lane >> 4;
  int fo = (lane & 15) * 8;
  if (b < 5000) {
    int node = b * 4 + wv;
    // dual: chains 0 and 4 interleaved in ydual (stride 256; Y4 = Y0 + 128)
    int beg = indptr[node], end = indptr[node + 1];
    const u16* __restrict__ Y0 = p.Y[0];
    const u16* __restrict__ Y4 = p.Y[4];
    int st = p.ystride[0];
    f32x2 a0[4], a4[4];
#pragma unroll
    for (int j = 0; j < 4; j++) { a0[j] = (f32x2)(0.f); a4[j] = (f32x2)(0.f); }
    int e = beg + g;
    for (; e + 4 < end; e += 8) {
      u32 sa = ent[e];
      u32 sb = ent[e + 4];
      size_t ra = (size_t)(sa & 0xffffu) * st + fo;
      size_t rb = (size_t)(sb & 0xffffu) * st + fo;
      uint4 va0 = *(const uint4*)(Y0 + ra);
      uint4 va4 = *(const uint4*)(Y4 + ra);
      uint4 vb0 = *(const uint4*)(Y0 + rb);
      uint4 vb4 = *(const uint4*)(Y4 + rb);
      float ca = __uint_as_float(sa & 0xffff0000u);
      float cb = __uint_as_float(sb & 0xffff0000u);
      fma8p(a0, va0, ca); fma8p(a4, va4, ca);
      fma8p(a0, vb0, cb); fma8p(a4, vb4, cb);
    }
    if (e < end) {
      u32 sc = ent[e];
      float cf = __uint_as_float(sc & 0xffff0000u);
      size_t ro = (size_t)(sc & 0xffffu) * st + fo;
      uint4 v0 = *(const uint4*)(Y0 + ro);
      uint4 v4 = *(const uint4*)(Y4 + ro);
      fma8p(a0, v0, cf);
      fma8p(a4, v4, cf);
    }
    float* f0 = (float*)a0;
    float* f4 = (float*)a4;
#pragma unroll
    for (int j = 0; j < 8; j++) {
      f0[j] += __shfl_xor(f0[j], 16);
      f0[j] += __shfl_xor(f0[j], 32);
      f4[j] += __shfl_xor(f4[j], 16);
      f4[j] += __shfl_xor(f4[j], 32);
    }
    if (g == 0) {
      float di = dinv[node];
      float d2 = di * di;
      fin_chain(f0, Y0, st, node, fo, d2, p.bias[0], p.Xo[0]);
      fin_chain(f4, Y4, st, node, fo, d2, p.bias[4], p.Xo[4]);
    }
  } else {
    int mb = b - 5000;
    int s = 1 + mb / 1250;       // chain == edge set, 1..3
    int node = (mb % 1250) * 16 + wv * 4 + g;  // 1250*16 == NN exactly
    const int* ip = indptr + s * (NN + 1);
    int eb = (s == 1) ? entoff.y : ((s == 2) ? entoff.z : entoff.w);
    const u16* __restrict__ Y = p.Y[s];
    int st = p.ystride[s];
    int beg = ip[node], end = ip[node + 1];
    const u32* __restrict__ ev = ent + eb;
    f32x2 a[4];
#pragma unroll
    for (int j = 0; j < 4; j++) a[j] = (f32x2)(0.f);
    for (int e = beg; e < end; e++) {
      u32 sc = ev[e];  // same addr across the 16-lane group -> one fetch
      uint4 v = *(const uint4*)(Y + (size_t)(sc & 0xffffu) * st + fo);
      fma8p(a, v, __uint_as_float(sc & 0xffff0000u));
    }
    float di = dinv[s * NN + node];
    float d2 = di * di;
    fin_chain((float*)a, Y, st, node, fo, d2, p.bias[s], p.Xo[s]);
  }
}

// fused graph-norm: grid (NG, NCH, 4 feature-chunks), 256 thr = 16 feature-pairs
// x 16 row-streams. Two passes over the graph's contiguous row slab (batch is
// sorted): stats via LDS tree (zero atomics), then normalize+leaky -> Xn and
// per-graph M-row by DIRECT store (each (g,col) owned by exactly one block).
__global__ __launch_bounds__(256) void k_norm2(ZP p, const int* __restrict__ gstart,
                                               const int* __restrict__ counts,
                                               float* __restrict__ Ml) {
  int g = blockIdx.x, zi = blockIdx.y, fc = blockIdx.z;
  const u16* __restrict__ X = p.Xo[zi];
  u16* __restrict__ Xn = p.Xn[zi];
  int t = threadIdx.x;
  int fj = t & 15;
  int f2 = fc * 32 + fj * 2;
  int rh = t >> 4;  // 16 row streams
  int start = gstart[g], cnt = counts[g];
  __shared__ float red[4][16][17];
  float s0 = 0.f, s1 = 0.f, q0 = 0.f, q1 = 0.f;
  for (int i = rh; i < cnt; i += 16) {
    u32 v = *(const u32*)(X + (size_t)(start + i) * NH + f2);
    float v0 = __uint_as_float(v << 16), v1 = __uint_as_float(v & 0xffff0000u);
    s0 += v0; q0 += v0 * v0;
    s1 += v1; q1 += v1 * v1;
  }
  red[0][rh][fj] = s0; red[1][rh][fj] = s1;
  red[2][rh][fj] = q0; red[3][rh][fj] = q1;
  __syncthreads();
#pragma unroll
  for (int off = 8; off >= 1; off >>= 1) {
    if (rh < off) {
      red[0][rh][fj] += red[0][rh + off][fj];
      red[1][rh][fj] += red[1][rh + off][fj];
      red[2][rh][fj] += red[2][rh + off][fj];
      red[3][rh][fj] += red[3][rh + off][fj];
    }
    __syncthreads();
  }
  float cntf = fmaxf((float)cnt, 1.f);
  float w0 = p.gw[zi][f2], w1 = p.gw[zi][f2 + 1];
  float b0 = p.gb[zi][f2], b1 = p.gb[zi][f2 + 1];
  float ms0 = p.gms[zi][f2], ms1 = p.gms[zi][f2 + 1];
  float mean0 = red[0][0][fj] / cntf, mean1 = red[1][0][fj] / cntf;
  float var0 = red[2][0][fj] / cntf - (2.f * ms0 - ms0 * ms0) * mean0 * mean0;
  float var1 = red[3][0][fj] / cntf - (2.f * ms1 - ms1 * ms1) * mean1 * mean1;
  float inv0 = rsqrtf(var0 + GEPS), inv1 = rsqrtf(var1 + GEPS);
  __syncthreads();  // all reads of red done before reuse
  float m0 = 0.f, m1 = 0.f;
  for (int i = rh; i < cnt; i += 16) {
    size_t ro = (size_t)(start + i) * NH + f2;
    u32 v = *(const u32*)(X + ro);
    float v0 = __uint_as_float(v << 16), v1 = __uint_as_float(v & 0xffff0000u);
    float o0 = w0 * (v0 - ms0 * mean0) * inv0 + b0;
    float o1 = w1 * (v1 - ms1 * mean1) * inv1 + b1;
    o0 = (o0 >= 0.f) ? o0 : GSLOPE * o0;
    o1 = (o1 >= 0.f) ? o1 : GSLOPE * o1;
    if (Xn) *(u32*)(Xn + ro) = (u32)f2bf(o0) | ((u32)f2bf(o1) << 16);
    m0 += o0; m1 += o1;
  }
  red[0][rh][fj] = m0; red[1][rh][fj] = m1;
  __syncthreads();
#pragma unroll
  for (int off = 8; off >= 1; off >>= 1) {
    if (rh < off) {
      red[0][rh][fj] += red[0][rh + off][fj];
      red[1][rh][fj] += red[1][rh + off][fj];
    }
    __syncthreads();
  }
  if (rh == 0) {
    int col = p.colbase[zi] + f2;
    Ml[(size_t)g * 640 + col] = red[0][0][fj];
    Ml[(size_t)g * 640 + col + 1] = red[1][0][fj];
  }
}

// out[g][f] = mean_l(M[l][g][:] @ mergeW[:,f]) / cnt + mergeb[f]
__global__ __launch_bounds__(256) void k_mergeout(const float* __restrict__ M,
                                                  const float* __restrict__ mergeW,
                                                  const float* __restrict__ mergeb,
                                                  const int* __restrict__ counts,
                                                  float* __restrict__ out) {
  int g = blockIdx.x;
  int f = threadIdx.x & 127, h = threadIdx.x >> 7;
  __shared__ float mrow[640];
  __shared__ float red[128];
  float acc = 0.f;
  for (int l = 0; l < NLAY; l++) {
    const float* Mr = M + ((size_t)l * NG + g) * 640;
    for (int i = threadIdx.x; i < 640; i += 256) mrow[i] = Mr[i];
    __syncthreads();
    float s = 0.f;
    int k0 = h * 320;
#pragma unroll 8
    for (int k = k0; k < k0 + 320; k++) s += mrow[k] * mergeW[(size_t)k * NH + f];
    if (h) red[f] = s;
    __syncthreads();
    if (!h) acc += s + red[f];
    __syncthreads();
  }
  if (!h) {
    float cnt = fmaxf((float)counts[g], 1.f);
    out[(size_t)g * NH + f] = acc / (3.f * cnt) + mergeb[f];
  }
}

// ---------------- host ----------------

struct Offs {
  size_t counts, gstart, deg, M, dinv, indptr, cursor, ent, wt, ydual;
  size_t yb[NCH], xo[NCH], xn[NCH];
  size_t memset1_off, memset1_len, total;
};

static size_t build_offs(Offs& o, int Etot) {
  size_t off = 0;
  auto alloc = [&](size_t bytes) -> size_t {
    off = (off + 255) & ~(size_t)255;
    size_t s = off;
    off += bytes;
    return s;
  };
  o.counts = alloc(NG * 4);
  o.gstart = alloc(NG * 4);
  o.deg = alloc((size_t)4 * NN * 4);
  o.memset1_off = o.deg;
  o.memset1_len = (size_t)4 * NN * 4;  // only deg needs zeroing
  o.M = alloc((size_t)NLAY * NG * 640 * 4);  // fully overwritten by k_norm2
  o.dinv = alloc((size_t)4 * NN * 4);
  o.indptr = alloc((size_t)4 * (NN + 1) * 4);
  o.cursor = alloc((size_t)4 * (NN + 1) * 4);
  o.ent = alloc((size_t)Etot * 4);  // packed 4B entries
  o.wt = alloc((size_t)7 * NH * NH * 2);
  o.ydual = alloc((size_t)NN * 256 * 2);  // chains 0&4 interleaved
  for (int i = 1; i < 4; i++) o.yb[i] = alloc((size_t)NN * NH * 2);
  for (int i = 0; i < NCH; i++) {
    o.xo[i] = alloc((size_t)NN * NH * 2);
    o.xn[i] = alloc((size_t)NNP * NH * 2);
  }
  o.total = off;
  return off;
}

extern "C" void kernel_launch(void* const* d_in, const int* in_sizes, int n_in,
                              void* d_out, int out_size, void* d_ws, size_t ws_size,
                              hipStream_t stream) {
  if (n_in < 21) return;
  const float* x = (const float*)d_in[0];
  const float* embW = (const float*)d_in[1];
  const float* embb = (const float*)d_in[2];
  const float* mainW = (const float*)d_in[3];
  const float* mainb = (const float*)d_in[4];
  const float* maingw = (const float*)d_in[5];
  const float* maingb = (const float*)d_in[6];
  const float* maingms = (const float*)d_in[7];
  const float* locW = (const float*)d_in[8];
  const float* locb = (const float*)d_in[9];
  const float* locgw = (const float*)d_in[10];
  const float* locgb = (const float*)d_in[11];
  const float* locgms = (const float*)d_in[12];
  const float* mergeW = (const float*)d_in[13];
  const float* mergeb = (const float*)d_in[14];
  const int* edge_index = (const int*)d_in[15];
  // d_in[16] = edges0: permutation of edge_index under segment_sum -> reuse set 0
  const int* edges1 = (const int*)d_in[17];
  const int* edges2 = (const int*)d_in[18];
  const int* edges3 = (const int*)d_in[19];
  const int* batch = (const int*)d_in[20];

  int E0 = in_sizes[15] / 2;
  int E1 = in_sizes[17] / 2, E2 = in_sizes[18] / 2, E3 = in_sizes[19] / 2;
  int Etot = E0 + E1 + E2 + E3;
  int maxE = E0 > E1 ? E0 : E1;
  maxE = maxE > E2 ? maxE : E2;
  maxE = maxE > E3 ? maxE : E3;

  Offs o;
  if (build_offs(o, Etot) > ws_size) return;  // fail visibly

  char* ws = (char*)d_ws;
  int* counts = (int*)(ws + o.counts);
  int* gstart = (int*)(ws + o.gstart);
  int* deg = (int*)(ws + o.deg);
  float* M = (float*)(ws + o.M);
  float* dinv = (float*)(ws + o.dinv);
  int* indptr = (int*)(ws + o.indptr);
  int* cursor = (int*)(ws + o.cursor);
  u32* ent = (u32*)(ws + o.ent);
  u16* wt = (u16*)(ws + o.wt);
  u16* ydual = (u16*)(ws + o.ydual);
  u16 *yb[NCH], *xo[NCH], *xn[NCH];
  for (int i = 1; i < 4; i++) yb[i] = (u16*)(ws + o.yb[i]);
  for (int i = 0; i < NCH; i++) {
    xo[i] = (u16*)(ws + o.xo[i]);
    xn[i] = (u16*)(ws + o.xn[i]);
  }

  ES4 es;
  es.e[0] = edge_index; es.e[1] = edges1; es.e[2] = edges2; es.e[3] = edges3;
  es.cnt[0] = E0; es.cnt[1] = E1; es.cnt[2] = E2; es.cnt[3] = E3;
  es.off[0] = 0; es.off[1] = E0; es.off[2] = E0 + E1; es.off[3] = E0 + E1 + E2;
  int4 entoff = make_int4(0, E0, E0 + E1, E0 + E1 + E2);

  hipMemsetAsync(ws + o.memset1_off, 0, o.memset1_len, stream);  // deg only
  k_setup<<<dim3((maxE + 255) / 256, 11), 256, 0, stream>>>(es, deg, embW, locW, mainW, wt);
  k_scan<<<5, 1024, 0, stream>>>(deg, indptr, cursor, dinv, batch, counts, gstart);
  k_fill<<<dim3((maxE + 255) / 256, 4), 256, 0, stream>>>(es, dinv, cursor, ent);

  const int nrb = (NN + 63) / 64;  // 313

  // fused embedding + layer-0 GEMMs -> ydual (both halves)
  k_gemm0<<<nrb, 256, 0, stream>>>(x, wt, embb, ydual);

  for (int l = 0; l < NLAY; l++) {
    ZP p = {};
    for (int zi = 0; zi < NCH; zi++) {
      bool isMain = (zi == 4);
      p.A[zi] = (const u16*)xn[zi];
      p.W[zi] = wt + (size_t)((isMain ? 4 : 1) + l) * NH * NH;
      if (zi == 0) { p.Y[0] = ydual; p.ystride[0] = 256; }
      else if (zi == 4) { p.Y[4] = ydual + 128; p.ystride[4] = 256; }
      else { p.Y[zi] = yb[zi]; p.ystride[zi] = 128; }
      p.Xo[zi] = xo[zi];
      p.Xn[zi] = (l == NLAY - 1) ? (u16*)nullptr : xn[zi];
      p.bias[zi] = (isMain ? mainb : locb) + (size_t)l * NH;
      p.gw[zi] = (isMain ? maingw : locgw) + (size_t)l * NH;
      p.gb[zi] = (isMain ? maingb : locgb) + (size_t)l * NH;
      p.gms[zi] = (isMain ? maingms : locgms) + (size_t)l * NH;
      p.colbase[zi] = isMain ? 512 : zi * NH;
    }
    if (l == 0) {
      // k_gemm0 already produced ydual; MST chains gather from chain-0 half
      p.Y[1] = ydual; p.Y[2] = ydual; p.Y[3] = ydual;
      p.ystride[1] = p.ystride[2] = p.ystride[3] = 256;
    } else {
      k_gemm_bf<<<dim3(nrb, NCH), 256, 0, stream>>>(p);
    }
    k_agg2<<<8750, 256, 0, stream>>>(p, indptr, ent, dinv, entoff);
    k_norm2<<<dim3(NG, NCH, 4), 256, 0, stream>>>(p, gstart, counts,
                                                  M + (size_t)l * NG * 640);
  }

  k_mergeout<<<NG, 256, 0, stream>>>(M, mergeW, mergeb, counts, (float*)d_out);
}